// Round 3
// baseline (387.315 us; speedup 1.0000x reference)
//
#include <hip/hip_runtime.h>
#include <hip/hip_bf16.h>

#define B_DIM 64
#define M_DIM 8192
#define V_DIM 128
#define EPS 1e-8f
#define KCAP 2048
#define NT2 1024

// monotone float->uint key map (order-preserving, invertible)
__device__ __forceinline__ unsigned int f2key(float f) {
    unsigned int u = __float_as_uint(f);
    return (u & 0x80000000u) ? ~u : (u | 0x80000000u);
}
__device__ __forceinline__ float key2f(unsigned int k) {
    return (k & 0x80000000u) ? __uint_as_float(k & 0x7FFFFFFFu)
                             : __uint_as_float(~k);
}

// ---------------- Kernel 1: cosine similarity -> radix keys ----------------
// grid (M/256, B), block 256 (4 waves). 16 lanes per row, 2 float4/lane:
// 4 rows per wave per t-iter, 16 t-iters -> 256 rows/block.
__global__ void sim_kernel(const float* __restrict__ mem,
                           const float* __restrict__ v,
                           unsigned int* __restrict__ keys_out) {
    const int b    = blockIdx.y;
    const int m0   = blockIdx.x * 256;
    const int tid  = threadIdx.x;
    const int wave = tid >> 6;
    const int lane = tid & 63;
    const int rw   = lane >> 4;   // row within wave (0..3)
    const int sub  = lane & 15;   // 16 lanes per row

    __shared__ float vs[V_DIM];
    __shared__ float s_invbn;

    if (tid < V_DIM) vs[tid] = v[b * V_DIM + tid] + EPS;
    __syncthreads();

    if (tid < 64) {
        float x0 = vs[tid], x1 = vs[tid + 64];
        float s = x0 * x0 + x1 * x1;
#pragma unroll
        for (int mk = 32; mk; mk >>= 1) s += __shfl_xor(s, mk, 64);
        if (tid == 0) s_invbn = 1.0f / sqrtf(s);   // denom >> EPS always here
    }
    __syncthreads();

    // per-lane v fragment in registers (cols sub*4.. and sub*4+64..)
    const float4 va = *reinterpret_cast<const float4*>(&vs[sub * 4]);
    const float4 vb = *reinterpret_cast<const float4*>(&vs[sub * 4 + 64]);
    const float invbn = s_invbn;

#pragma unroll 4
    for (int t = 0; t < 16; ++t) {
        const int m = m0 + t * 16 + wave * 4 + rw;
        const float4* rp =
            reinterpret_cast<const float4*>(mem + ((size_t)b * M_DIM + m) * V_DIM);
        float4 x0 = rp[sub];
        float4 x1 = rp[sub + 16];
        // NOTE: per-element +EPS dropped: |delta sim| ~1e-6 << 0.28 threshold
        float dot = x0.x * va.x + x0.y * va.y + x0.z * va.z + x0.w * va.w
                  + x1.x * vb.x + x1.y * vb.y + x1.z * vb.z + x1.w * vb.w;
        float ss  = x0.x * x0.x + x0.y * x0.y + x0.z * x0.z + x0.w * x0.w
                  + x1.x * x1.x + x1.y * x1.y + x1.z * x1.z + x1.w * x1.w;
#pragma unroll
        for (int mk = 8; mk; mk >>= 1) {
            dot += __shfl_xor(dot, mk, 16);
            ss  += __shfl_xor(ss,  mk, 16);
        }
        if (sub == 0) {
            float sim = dot * rsqrtf(ss) * invbn;
            keys_out[(size_t)b * M_DIM + m] = f2key(sim);
        }
    }
}

// ---------------- Kernel 2: exact top-k select + fused write/read ----------
// One block per batch, 1024 threads (16 waves). Byte radix-select with
// wave-aggregated (ballot) histogram atomics and a single-wave shfl-based
// 256-bucket suffix scan (no barriers inside the scan).
__global__ __launch_bounds__(NT2)
void topk_read_kernel(const float* __restrict__ mem,
                      const float* __restrict__ v,
                      const unsigned int* __restrict__ keys_in,
                      const int* __restrict__ topk_p,
                      float* __restrict__ out) {
    const int b    = blockIdx.x;
    const int tid  = threadIdx.x;
    const int lane = tid & 63;
    const int wv   = tid >> 6;

    __shared__ unsigned int keys[M_DIM];      // 32 KB
    __shared__ unsigned int hist[256];        // 1 KB
    __shared__ unsigned int s_prefix;
    __shared__ int s_k;
    __shared__ int s_cnt;
    __shared__ int   s_idx[KCAP];             // 8 KB
    __shared__ float s_w[KCAP];               // 8 KB
    __shared__ float s_sumw2;
    __shared__ float s_acc[NT2];              // 4 KB

    // coalesced key load (uint4)
    {
        const uint4* kin = reinterpret_cast<const uint4*>(keys_in + (size_t)b * M_DIM);
        uint4* kl = reinterpret_cast<uint4*>(keys);
        for (int i = tid; i < M_DIM / 4; i += NT2) kl[i] = kin[i];
    }
    if (tid == 0) { s_prefix = 0u; s_k = topk_p[0]; s_cnt = 0; }
    __syncthreads();

    for (int p = 3; p >= 0; --p) {
        if (tid < 256) hist[tid] = 0u;
        __syncthreads();
        const unsigned int dm = (p == 3) ? 0u : (0xFFFFFFFFu << ((p + 1) * 8));
        const unsigned int pf = s_prefix;
        const int k_cur = s_k;

        // wave-aggregated histogram: one atomic per distinct bucket per wave
        for (int i = tid; i < M_DIM; i += NT2) {
            unsigned int ky = keys[i];
            bool ok = ((ky & dm) == pf);
            int bucket = (int)((ky >> (p * 8)) & 0xFFu);
            unsigned long long act = __ballot(ok);
            while (act) {
                int leader = __ffsll((long long)act) - 1;
                int bb = __shfl(bucket, leader, 64);
                unsigned long long match = __ballot(ok && bucket == bb);
                if (lane == leader)
                    atomicAdd(&hist[bb], (unsigned int)__popcll(match));
                act &= ~match;
            }
        }
        __syncthreads();

        // single-wave 256-bucket suffix scan + kth-bucket locate (no barriers)
        if (wv == 0) {
            int c0 = (int)hist[lane * 4 + 0];
            int c1 = (int)hist[lane * 4 + 1];
            int c2 = (int)hist[lane * 4 + 2];
            int c3 = (int)hist[lane * 4 + 3];
            int s3 = c3, s2 = c2 + s3, s1 = c1 + s2, s0 = c0 + s1;
            int T = s0, x = T;
#pragma unroll
            for (int off = 1; off < 64; off <<= 1) {
                int y = __shfl_down(x, off, 64);
                if (lane + off < 64) x += y;
            }
            int excl = x - T;                    // sum over lanes > lane
            int S0 = s0 + excl, S1 = s1 + excl;
            int S2 = s2 + excl, S3 = s3 + excl, S4 = excl;
            int t = -1, krem = 0;
            if (S0 >= k_cur && S1 < k_cur) { t = 0; krem = k_cur - S1; }
            else if (S1 >= k_cur && S2 < k_cur) { t = 1; krem = k_cur - S2; }
            else if (S2 >= k_cur && S3 < k_cur) { t = 2; krem = k_cur - S3; }
            else if (S3 >= k_cur && S4 < k_cur) { t = 3; krem = k_cur - S4; }
            if (t >= 0) {
                s_prefix = pf | ((unsigned int)(lane * 4 + t) << (p * 8));
                s_k = krem;
            }
        }
        __syncthreads();
    }
    const unsigned int kth = s_prefix;   // exact key of kth-largest

    // compact kept entries: sim >= kth  <=>  key >= kth (monotone map)
    for (int i = tid; i < M_DIM; i += NT2) {
        unsigned int ky = keys[i];
        if (ky >= kth) {
            int pos = atomicAdd(&s_cnt, 1);
            if (pos < KCAP) { s_idx[pos] = i; s_w[pos] = key2f(ky); }
        }
    }
    __syncthreads();
    const int cnt = min(s_cnt, KCAP);

    if (tid < 64) {
        float s = 0.f;
        for (int i = tid; i < cnt; i += 64) s += s_w[i] * s_w[i];
#pragma unroll
        for (int mk = 32; mk; mk >>= 1) s += __shfl_xor(s, mk, 64);
        if (tid == 0) s_sumw2 = s;
    }
    __syncthreads();

    // read accumulation: 128 cols, 8 threads/col over kept rows
    const int col = tid & 127;
    const int grp = tid >> 7;     // 0..7
    const float* mb = mem + (size_t)b * M_DIM * V_DIM;
    float acc = 0.f;
    for (int j = grp; j < cnt; j += 8)
        acc += s_w[j] * mb[(size_t)s_idx[j] * V_DIM + col];
    s_acc[tid] = acc;
    __syncthreads();
    if (tid < 128) {
        float r = s_sumw2 * v[b * V_DIM + tid];
#pragma unroll
        for (int g = 0; g < 8; ++g) r += s_acc[tid + 128 * g];
        out[b * V_DIM + tid] = r;
    }
}

extern "C" void kernel_launch(void* const* d_in, const int* in_sizes, int n_in,
                              void* d_out, int out_size, void* d_ws, size_t ws_size,
                              hipStream_t stream) {
    const float* mem  = (const float*)d_in[0];
    const float* v    = (const float*)d_in[1];
    const int*   topk = (const int*)d_in[2];
    float* out        = (float*)d_out;
    unsigned int* keys = (unsigned int*)d_ws;   // B*M uints = 2 MB

    dim3 grid1(M_DIM / 256, B_DIM);
    sim_kernel<<<grid1, 256, 0, stream>>>(mem, v, keys);

    topk_read_kernel<<<B_DIM, NT2, 0, stream>>>(mem, v, keys, topk, out);
}

// Round 4
// 378.393 us; speedup vs baseline: 1.0236x; 1.0236x over previous
//
#include <hip/hip_runtime.h>
#include <hip/hip_bf16.h>

#define B_DIM 64
#define M_DIM 8192
#define V_DIM 128
#define EPS 1e-8f
#define KCAP 2048

// monotone float->uint key map (order-preserving, invertible)
__device__ __forceinline__ unsigned int f2key(float f) {
    unsigned int u = __float_as_uint(f);
    return (u & 0x80000000u) ? ~u : (u | 0x80000000u);
}
__device__ __forceinline__ float key2f(unsigned int k) {
    return (k & 0x80000000u) ? __uint_as_float(k & 0x7FFFFFFFu)
                             : __uint_as_float(~k);
}

// ---------------- Kernel 1: cosine similarity -> radix keys ----------------
// R2's proven config: grid (M/64, B), block 256 (4 waves). 16 lanes/row,
// 2 float4/lane -> 4 rows per wave per iter, 4 iters -> 64 rows/block.
__global__ __launch_bounds__(256)
void sim_kernel(const float* __restrict__ mem,
                const float* __restrict__ v,
                unsigned int* __restrict__ keys_out) {
    const int b    = blockIdx.y;
    const int m0   = blockIdx.x * 64;
    const int tid  = threadIdx.x;
    const int wave = tid >> 6;
    const int lane = tid & 63;
    const int rw   = lane >> 4;   // row within wave (0..3)
    const int sub  = lane & 15;   // 16 lanes per row

    __shared__ float vs[V_DIM];
    __shared__ float s_invbn;

    if (tid < V_DIM) vs[tid] = v[b * V_DIM + tid] + EPS;
    __syncthreads();

    if (tid < 64) {
        float x0 = vs[tid], x1 = vs[tid + 64];
        float s = x0 * x0 + x1 * x1;
#pragma unroll
        for (int mk = 32; mk; mk >>= 1) s += __shfl_xor(s, mk, 64);
        if (tid == 0) s_invbn = 1.0f / sqrtf(s);   // denom >> EPS always here
    }
    __syncthreads();

    const float4 va = *reinterpret_cast<const float4*>(&vs[sub * 4]);
    const float4 vb = *reinterpret_cast<const float4*>(&vs[sub * 4 + 64]);
    const float invbn = s_invbn;

#pragma unroll
    for (int t = 0; t < 4; ++t) {
        const int m = m0 + t * 16 + wave * 4 + rw;
        const float4* rp =
            reinterpret_cast<const float4*>(mem + ((size_t)b * M_DIM + m) * V_DIM);
        float4 x0 = rp[sub];
        float4 x1 = rp[sub + 16];
        float a0 = x0.x + EPS, a1 = x0.y + EPS, a2 = x0.z + EPS, a3 = x0.w + EPS;
        float a4 = x1.x + EPS, a5 = x1.y + EPS, a6 = x1.z + EPS, a7 = x1.w + EPS;
        float dot = a0 * va.x + a1 * va.y + a2 * va.z + a3 * va.w
                  + a4 * vb.x + a5 * vb.y + a6 * vb.z + a7 * vb.w;
        float ss  = a0 * a0 + a1 * a1 + a2 * a2 + a3 * a3
                  + a4 * a4 + a5 * a5 + a6 * a6 + a7 * a7;
#pragma unroll
        for (int mk = 8; mk; mk >>= 1) {
            dot += __shfl_xor(dot, mk, 16);
            ss  += __shfl_xor(ss,  mk, 16);
        }
        if (sub == 0) {
            float sim = dot * rsqrtf(ss) * invbn;
            keys_out[(size_t)b * M_DIM + m] = f2key(sim);
        }
    }
}

// ---------------- Kernel 2: exact top-k select + fused write/read ----------
// One block per batch (256 thr, 4 waves). Byte radix-select: per-wave private
// histograms (simple LDS atomics) + barrier-free single-wave shfl suffix scan.
__global__ __launch_bounds__(256)
void topk_read_kernel(const float* __restrict__ mem,
                      const float* __restrict__ v,
                      const unsigned int* __restrict__ keys_in,
                      const int* __restrict__ topk_p,
                      float* __restrict__ out) {
    const int b    = blockIdx.x;
    const int tid  = threadIdx.x;
    const int NT   = 256;
    const int lane = tid & 63;
    const int wv   = tid >> 6;

    __shared__ unsigned int keys[M_DIM];      // 32 KB
    __shared__ unsigned int hist[4 * 256];    // 4 KB, per-wave private
    __shared__ unsigned int s_prefix;
    __shared__ int s_k;
    __shared__ int s_cnt;
    __shared__ int   s_idx[KCAP];             // 8 KB
    __shared__ float s_w[KCAP];               // 8 KB
    __shared__ float s_sumw2;
    __shared__ float s_acc[256];

    // coalesced key staging (uint4)
    {
        const uint4* kin = reinterpret_cast<const uint4*>(keys_in + (size_t)b * M_DIM);
        uint4* kl = reinterpret_cast<uint4*>(keys);
        for (int i = tid; i < M_DIM / 4; i += NT) kl[i] = kin[i];
    }
    if (tid == 0) { s_prefix = 0u; s_k = topk_p[0]; s_cnt = 0; }
    __syncthreads();

    for (int p = 3; p >= 0; --p) {
#pragma unroll
        for (int h = tid; h < 1024; h += NT) hist[h] = 0u;
        __syncthreads();
        const unsigned int dm = (p == 3) ? 0u : (0xFFFFFFFFu << ((p + 1) * 8));
        const unsigned int pf = s_prefix;
        const int k_cur = s_k;
        for (int i = tid; i < M_DIM; i += NT) {
            unsigned int ky = keys[i];
            if ((ky & dm) == pf)
                atomicAdd(&hist[wv * 256 + ((ky >> (p * 8)) & 0xFFu)], 1u);
        }
        __syncthreads();

        // single-wave suffix scan over 256 buckets (lane owns 4 buckets)
        if (wv == 0) {
            int c0 = (int)(hist[lane * 4 + 0] + hist[256 + lane * 4 + 0]
                         + hist[512 + lane * 4 + 0] + hist[768 + lane * 4 + 0]);
            int c1 = (int)(hist[lane * 4 + 1] + hist[256 + lane * 4 + 1]
                         + hist[512 + lane * 4 + 1] + hist[768 + lane * 4 + 1]);
            int c2 = (int)(hist[lane * 4 + 2] + hist[256 + lane * 4 + 2]
                         + hist[512 + lane * 4 + 2] + hist[768 + lane * 4 + 2]);
            int c3 = (int)(hist[lane * 4 + 3] + hist[256 + lane * 4 + 3]
                         + hist[512 + lane * 4 + 3] + hist[768 + lane * 4 + 3]);
            int s3 = c3, s2 = c2 + s3, s1 = c1 + s2, s0 = c0 + s1;
            int T = s0, x = T;
#pragma unroll
            for (int off = 1; off < 64; off <<= 1) {
                int y = __shfl_down(x, off, 64);
                if (lane + off < 64) x += y;
            }
            int excl = x - T;                    // sum over lanes > lane
            int S0 = s0 + excl, S1 = s1 + excl;
            int S2 = s2 + excl, S3 = s3 + excl, S4 = excl;
            int t = -1, krem = 0;
            if (S0 >= k_cur && S1 < k_cur) { t = 0; krem = k_cur - S1; }
            else if (S1 >= k_cur && S2 < k_cur) { t = 1; krem = k_cur - S2; }
            else if (S2 >= k_cur && S3 < k_cur) { t = 2; krem = k_cur - S3; }
            else if (S3 >= k_cur && S4 < k_cur) { t = 3; krem = k_cur - S4; }
            if (t >= 0) {
                s_prefix = pf | ((unsigned int)(lane * 4 + t) << (p * 8));
                s_k = krem;
            }
        }
        __syncthreads();
    }
    const unsigned int kth = s_prefix;   // exact key of kth-largest

    // compact kept entries: sim >= kth  <=>  key >= kth (monotone map)
    for (int i = tid; i < M_DIM; i += NT) {
        unsigned int ky = keys[i];
        if (ky >= kth) {
            int pos = atomicAdd(&s_cnt, 1);
            if (pos < KCAP) { s_idx[pos] = i; s_w[pos] = key2f(ky); }
        }
    }
    __syncthreads();
    const int cnt = min(s_cnt, KCAP);

    if (tid < 64) {
        float s = 0.f;
        for (int i = tid; i < cnt; i += 64) s += s_w[i] * s_w[i];
#pragma unroll
        for (int mk = 32; mk; mk >>= 1) s += __shfl_xor(s, mk, 64);
        if (tid == 0) s_sumw2 = s;
    }
    __syncthreads();

    // read accumulation: 128 cols, 2 threads/col, 4-way unrolled over rows
    const int col  = tid & 127;
    const int half = tid >> 7;
    const float* mb = mem + (size_t)b * M_DIM * V_DIM;
    float a0 = 0.f, a1 = 0.f, a2 = 0.f, a3 = 0.f;
    int j = half;
    for (; j + 6 < cnt; j += 8) {
        a0 += s_w[j]     * mb[(size_t)s_idx[j]     * V_DIM + col];
        a1 += s_w[j + 2] * mb[(size_t)s_idx[j + 2] * V_DIM + col];
        a2 += s_w[j + 4] * mb[(size_t)s_idx[j + 4] * V_DIM + col];
        a3 += s_w[j + 6] * mb[(size_t)s_idx[j + 6] * V_DIM + col];
    }
    for (; j < cnt; j += 2)
        a0 += s_w[j] * mb[(size_t)s_idx[j] * V_DIM + col];
    s_acc[tid] = (a0 + a1) + (a2 + a3);
    __syncthreads();
    if (tid < 128)
        out[b * V_DIM + tid] =
            s_acc[tid] + s_acc[tid + 128] + s_sumw2 * v[b * V_DIM + tid];
}

extern "C" void kernel_launch(void* const* d_in, const int* in_sizes, int n_in,
                              void* d_out, int out_size, void* d_ws, size_t ws_size,
                              hipStream_t stream) {
    const float* mem  = (const float*)d_in[0];
    const float* v    = (const float*)d_in[1];
    const int*   topk = (const int*)d_in[2];
    float* out        = (float*)d_out;
    unsigned int* keys = (unsigned int*)d_ws;   // B*M uints = 2 MB

    dim3 grid1(M_DIM / 64, B_DIM);
    sim_kernel<<<grid1, 256, 0, stream>>>(mem, v, keys);

    topk_read_kernel<<<B_DIM, 256, 0, stream>>>(mem, v, keys, topk, out);
}